// Round 10
// baseline (68.313 us; speedup 1.0000x reference)
//
#include <hip/hip_runtime.h>

// ToeplitzMemoryProjection (HiPPO LagT, alpha=0.5 bilinear).
//
// Recurrence (exact in the truncated lower-tri Toeplitz algebra, verified
// rounds 1-9): with c = 1+0.25dt, g = (1-0.25dt)/c, beta = dt*u/c,
//   x_l[i] = g_l*(x_l[i-1] + x_{l-1}[i]) - x_{l-1}[i-1] + beta_l*[i==0]
//
// R10 = R9 (column-per-lane wavefront, KCH=32, SKEW=96, row-indexed ring
// RSLOT=128, LDS-only barriers) with the per-chunk stall windows collapsed:
//  - LAG-96 FLUSH: flush rows [bl-96, bl-65] (complete >= 1 chunk ago), so
//    the flush ds_read_b128 cluster issues at chunk START together with the
//    g and hb clusters -> ONE s_waitcnt lgkmcnt(0) per chunk (was 3 exposed
//    waits). Slot-residue proof: flush reads = bl+{32..63} mod 128; this
//    chunk's writes = bl+{-63..+31} mod 128 -> disjoint.
//  - hbm[s] = lane0 ? hb[s] : 0 precomputed in the cluster-wait shadow
//    (removes 1 cndmask from every tick).
//  - incremental ring write address: soff = (soff+256) & 32767 (+ const
//    column base) and asm ds_write_b32 -> 4 inst/tick for the staging write.
//  - bank audit: every LDS access pattern is at the conflict-free optimum
//    (writes 2 dwords/bank, flush b128 8 dwords/bank balanced, hb broadcast).

namespace {

constexpr int LLEN   = 1024;
constexpr int NCHAN  = 256;
constexpr int KCH    = 32;                 // ticks per chunk
constexpr int SKEW   = 96;                 // wave skew; 96-63=33 > KCH-1
constexpr int RSLOT  = 128;                // row slots per ring (pow2)
constexpr int NCHUNK = 44;                 // last flush: wave3 F=992 @ T0=1376
constexpr int GPAD   = 1152;               // g/b padded length

constexpr int G_OFF = 0;
constexpr int B_OFF = GPAD;
constexpr int R_OFF = 2 * GPAD;
constexpr int LDS_FLOATS = R_OFF + 4 * RSLOT * 64;
constexpr size_t LDS_BYTES = (size_t)LDS_FLOATS * 4;   // 140288 B

using f32x4 = __attribute__((ext_vector_type(4))) float;

__device__ __forceinline__ float dpp_shr1(float v) {
    // lane i <- lane i-1; lane 0 <- 0
    return __int_as_float(__builtin_amdgcn_update_dpp(
        0, __float_as_int(v), 0x138 /*WAVE_SHR1*/, 0xF, 0xF, false));
}
__device__ __forceinline__ unsigned lds_a(const void* p) {
    return (unsigned)(unsigned long long)p;
}
__device__ __forceinline__ void ds_rd32(float& d, unsigned a, int imm) {
    asm volatile("ds_read_b32 %0, %1 offset:%2" : "=v"(d) : "v"(a), "i"(imm));
}
__device__ __forceinline__ void ds_rd128(f32x4& d, unsigned a, int imm) {
    asm volatile("ds_read_b128 %0, %1 offset:%2" : "=v"(d) : "v"(a), "i"(imm));
}
__device__ __forceinline__ void ds_wr32(unsigned a, float x) {
    asm volatile("ds_write_b32 %0, %1" :: "v"(a), "v"(x));
}
__device__ __forceinline__ void wait_lgkm0_fence() {
    asm volatile("s_waitcnt lgkmcnt(0)" ::: "memory");
    __builtin_amdgcn_sched_barrier(0);
}
__device__ __forceinline__ void lds_barrier() {
    __builtin_amdgcn_sched_barrier(0);
    asm volatile("s_waitcnt lgkmcnt(0)" ::: "memory");
    __builtin_amdgcn_s_barrier();
    __builtin_amdgcn_sched_barrier(0);
}

// One chunk. TMODE: 0 = no ticks (flush-only tail), 1 = masked, 2 = fast.
template <bool W0, int TMODE>
__device__ __forceinline__ void chunk_body(
    const int T0, const int bl, const bool doF, const int lane,
    const unsigned g_base, const unsigned b_base,
    const unsigned lf_base, const unsigned my_base,
    float& prev_own, float& prev_left,
    float* __restrict__ out_fl)   // out + ch*256 + wave*64 + (lane&15)*4
{
    const int F = bl - 96;
    f32x4 tmp4[8];
    float gpre[KCH], hb[KCH];

    // ================== read clusters (one wait for all) ==================
    if (doF) {
        const unsigned fb = my_base +
            (unsigned)((((F & (RSLOT - 1)) + (lane >> 4)) << 8) + ((lane & 15) << 4));
        #pragma unroll
        for (int q = 0; q < 8; ++q) ds_rd128(tmp4[q], fb, q * 1024);
    }
    if (TMODE == 2) {
        const unsigned ga = g_base + 4u * (unsigned)(bl - lane);
        #pragma unroll
        for (int s = 0; s < KCH; ++s) ds_rd32(gpre[s], ga, 4 * s);
    } else if (TMODE == 1) {
        #pragma unroll
        for (int s = 0; s < KCH; ++s) {
            const int li = min(max(bl - lane + s, 0), LLEN - 1);
            ds_rd32(gpre[s], g_base + 4u * (unsigned)li, 0);
        }
    }
    if (TMODE > 0) {
        if (W0) {
            const unsigned ba = b_base + 4u * (unsigned)T0;  // pad covers to 1151
            #pragma unroll
            for (int q = 0; q < KCH / 4; ++q) {
                f32x4 t; ds_rd128(t, ba, 16 * q);
                hb[4*q+0] = t[0]; hb[4*q+1] = t[1];
                hb[4*q+2] = t[2]; hb[4*q+3] = t[3];
            }
        } else {
            // left ring col 63, rows bl..bl+31: (bl&127)+s <= 127, no wrap
            const unsigned ha = lf_base + (unsigned)(((bl & (RSLOT - 1)) << 8) + 252);
            #pragma unroll
            for (int s = 0; s < KCH; ++s) ds_rd32(hb[s], ha, s << 8);
        }
    }
    wait_lgkm0_fence();

    // ============================ ticks ===================================
    if (TMODE > 0) {
        const bool lane0 = (lane == 0);
        float hbm[KCH];
        #pragma unroll
        for (int s = 0; s < KCH; ++s) hbm[s] = lane0 ? hb[s] : 0.0f;

        unsigned soff = (unsigned)((((bl - lane) & (RSLOT - 1)) << 8));
        const unsigned colb = my_base + ((unsigned)lane << 2);
        #pragma unroll
        for (int s = 0; s < KCH; ++s) {
            const float u = dpp_shr1(prev_own);
            const float gg = gpre[s];
            float x, npl;
            if (W0) {
                const float t1 = fmaf(gg, prev_own, hbm[s] - prev_left);
                x = fmaf(gg, u, t1);
                npl = u;
            } else {
                const float ua = u + hbm[s];
                const float t1 = fmaf(gg, prev_own, -prev_left);
                x = fmaf(gg, ua, t1);
                npl = ua;
            }
            ds_wr32(colb + soff, x);            // OOB-row garbage: slot-safe
            soff = (soff + 256u) & 32767u;
            if (TMODE == 1) {
                const bool act = (unsigned)(bl - lane + s) < (unsigned)LLEN;
                prev_left = act ? npl : prev_left;
                prev_own  = act ? x   : prev_own;
            } else {
                prev_left = npl;
                prev_own  = x;
            }
        }
    }

    // ============================ stores ==================================
    if (doF) {
        float* ob = out_fl + (size_t)(F + (lane >> 4)) * (NCHAN * 256);
        #pragma unroll
        for (int q = 0; q < 8; ++q) {
            __builtin_nontemporal_store(tmp4[q], reinterpret_cast<f32x4*>(ob));
            ob += (size_t)4 * (NCHAN * 256);
        }
    }
}

__global__ __launch_bounds__(256, 1)
void toeplitz_scan(const float* __restrict__ vin,   // inputs (L, 256)
                   const float* __restrict__ dtin,  // dt     (L, 256)
                   float* __restrict__ out)         // (L, 256, 256)
{
    extern __shared__ float lds[];
    float* g_arr = lds + G_OFF;   // [GPAD]
    float* b_arr = lds + B_OFF;   // [GPAD]
    float* ring  = lds + R_OFF;   // [4][RSLOT][64], row-indexed slots

    const int ch  = blockIdx.x;
    const int tid = threadIdx.x;

    // ---- per-channel g[l], beta[l] (+ pad) ----
    #pragma unroll
    for (int k = 0; k < LLEN / 256; ++k) {
        const int l = tid + 256 * k;
        const float d = dtin[l * NCHAN + ch];
        const float u = vin[l * NCHAN + ch];
        const float ic = 1.0f / (1.0f + 0.25f * d);
        g_arr[l] = (1.0f - 0.25f * d) * ic;
        b_arr[l] = d * u * ic;
    }
    if (tid < GPAD - LLEN) {
        g_arr[LLEN + tid] = 1.0f;
        b_arr[LLEN + tid] = 0.0f;
    }
    __syncthreads();

    const int wave = tid >> 6, lane = tid & 63;
    const bool w0   = (wave == 0);
    const int wskew = wave * SKEW;

    const unsigned g_base  = lds_a(g_arr);
    const unsigned b_base  = lds_a(b_arr);
    const unsigned my_base = lds_a(ring + wave * (RSLOT * 64));
    const unsigned lf_base = lds_a(ring + (wave - 1) * (RSLOT * 64)); // wave>0

    float prev_own = 0.0f, prev_left = 0.0f;
    float* const out_fl = out + (size_t)(ch * 256 + wave * 64 + (lane & 15) * 4);

    for (int c = 0; c < NCHUNK; ++c) {
        const int T0 = c * KCH;
        const int bl = T0 - wskew;              // lane0's row (multiple of 32)
        const int F  = bl - 96;
        const bool doF   = (F >= 0) && (F <= LLEN - KCH);
        const bool ticks = (bl >= 0) && (bl <= 1056);
        const bool fast  = (bl >= 64) && (bl <= LLEN - KCH);

        if (ticks) {
            if (fast) {
                if (w0) chunk_body<true, 2>(T0, bl, doF, lane, g_base, b_base,
                                            lf_base, my_base, prev_own, prev_left, out_fl);
                else    chunk_body<false, 2>(T0, bl, doF, lane, g_base, b_base,
                                             lf_base, my_base, prev_own, prev_left, out_fl);
            } else {
                if (w0) chunk_body<true, 1>(T0, bl, doF, lane, g_base, b_base,
                                            lf_base, my_base, prev_own, prev_left, out_fl);
                else    chunk_body<false, 1>(T0, bl, doF, lane, g_base, b_base,
                                             lf_base, my_base, prev_own, prev_left, out_fl);
            }
        } else if (doF) {
            chunk_body<false, 0>(T0, bl, true, lane, g_base, b_base,
                                 lf_base, my_base, prev_own, prev_left, out_fl);
        }
        lds_barrier();
    }
}

} // namespace

extern "C" void kernel_launch(void* const* d_in, const int* in_sizes, int n_in,
                              void* d_out, int out_size, void* d_ws, size_t ws_size,
                              hipStream_t stream) {
    (void)in_sizes; (void)n_in; (void)d_ws; (void)ws_size; (void)out_size;
    const float* vin  = (const float*)d_in[0];   // "inputs"
    const float* dtin = (const float*)d_in[1];   // "dt"
    float* out = (float*)d_out;

    (void)hipFuncSetAttribute(reinterpret_cast<const void*>(toeplitz_scan),
                              hipFuncAttributeMaxDynamicSharedMemorySize,
                              (int)LDS_BYTES);

    toeplitz_scan<<<NCHAN, 256, LDS_BYTES, stream>>>(vin, dtin, out);
}